// Round 5
// baseline (1977.355 us; speedup 1.0000x reference)
//
#include <hip/hip_runtime.h>
#include <math.h>

typedef float f32x4 __attribute__((ext_vector_type(4)));
typedef __bf16 bf16x8 __attribute__((ext_vector_type(8)));
typedef unsigned short u16x8 __attribute__((ext_vector_type(8)));

static constexpr int Dm  = 2048;
static constexpr int Tm  = 2048;
static constexpr int Hm  = 16;
static constexpr int KVm = 8;
static constexpr int HDm = 128;
static constexpr int FFm = 6144;
static constexpr int Vm  = 32000;
static constexpr int QKVN = 4096;   // fused q|k|v column width

__device__ __forceinline__ float b2f(unsigned short u) {
  unsigned int x = ((unsigned int)u) << 16;
  return __builtin_bit_cast(float, x);
}
// native cast -> v_cvt_pk_bf16_f32 (RTNE); far fewer VALU than manual round
__device__ __forceinline__ unsigned short f2b(float f) {
  return __builtin_bit_cast(unsigned short, (__bf16)f);
}
__device__ __forceinline__ f32x4 mfma16x16x32(bf16x8 a, bf16x8 b, f32x4 c) {
  return __builtin_amdgcn_mfma_f32_16x16x32_bf16(a, b, c, 0, 0, 0);
}

// async global->LDS, 16B per lane; LDS dest = wave-uniform base + lane*16
__device__ __forceinline__ void gload16(const unsigned short* g, unsigned short* lds) {
  __builtin_amdgcn_global_load_lds(
      (const __attribute__((address_space(1))) unsigned int*)g,
      (__attribute__((address_space(3))) unsigned int*)lds, 16, 0, 0);
}

// bijective chunked XCD swizzle (m204)
__device__ __forceinline__ int xcd_swz(int o, int nwg) {
  int q = nwg >> 3, r8 = nwg & 7;
  int xcd = o & 7, pos = o >> 3;
  return (xcd < r8) ? xcd * (q + 1) + pos : r8 * (q + 1) + (xcd - r8) * q + pos;
}

// ---------------------------------------------------------------------------
__global__ void rope_tables_k(float* __restrict__ cosT, float* __restrict__ sinT) {
  int t = blockIdx.x;
  int i = threadIdx.x;      // 0..63
  double inv = pow(1000000.0, -(double)i / 64.0);
  double ang = (double)t * inv;
  cosT[t * 64 + i] = (float)cos(ang);
  sinT[t * 64 + i] = (float)sin(ang);
}

__global__ __launch_bounds__(256) void embed_k(const int* __restrict__ ids,
                                               const float* __restrict__ emb,
                                               float* __restrict__ x) {
  int t = blockIdx.x;
  int d0 = threadIdx.x * 8;
  int id = ids[t];
  const float* src = emb + (size_t)id * Dm + d0;
  float* dst = x + (size_t)t * Dm + d0;
  *(f32x4*)dst       = *(const f32x4*)src;
  *(f32x4*)(dst + 4) = *(const f32x4*)(src + 4);
}

// emb fp32 -> bf16 flat copy (for the logits GEMM's fast B path)
__global__ __launch_bounds__(256) void cvt_emb_k(const float* __restrict__ src,
                                                 unsigned short* __restrict__ dst) {
  size_t i = ((size_t)blockIdx.x * 256 + threadIdx.x) * 8;
  f32x4 a = *(const f32x4*)(src + i);
  f32x4 b = *(const f32x4*)(src + i + 4);
  u16x8 o;
  o[0] = f2b(a.x); o[1] = f2b(a.y); o[2] = f2b(a.z); o[3] = f2b(a.w);
  o[4] = f2b(b.x); o[5] = f2b(b.y); o[6] = f2b(b.z); o[7] = f2b(b.w);
  *(u16x8*)(dst + i) = o;
}

__global__ __launch_bounds__(256) void rmsnorm_k(const float* __restrict__ x,
                                                 const float* __restrict__ g,
                                                 unsigned short* __restrict__ y) {
  int t = blockIdx.x;
  const float* xr = x + (size_t)t * Dm;
  float vals[8];
  float s = 0.f;
#pragma unroll
  for (int i = 0; i < 8; ++i) {
    float vv = xr[threadIdx.x + i * 256];
    vals[i] = vv;
    s += vv * vv;
  }
#pragma unroll
  for (int off = 32; off; off >>= 1) s += __shfl_xor(s, off);
  __shared__ float red[4];
  if ((threadIdx.x & 63) == 0) red[threadIdx.x >> 6] = s;
  __syncthreads();
  s = (red[0] + red[1]) + (red[2] + red[3]);
  float r = rsqrtf(s * (1.f / Dm) + 1e-6f);
  unsigned short* yr = y + (size_t)t * Dm;
#pragma unroll
  for (int i = 0; i < 8; ++i) {
    int d = threadIdx.x + i * 256;
    yr[d] = f2b(vals[i] * r * g[d]);
  }
}

// Per-(t,head) RMSNorm over HD=128 then RoPE; rows at q + t*tstride + h*128.
__global__ __launch_bounds__(256) void qknorm_rope_k(unsigned short* __restrict__ q,
                                                     const float* __restrict__ nrm,
                                                     const float* __restrict__ cosT,
                                                     const float* __restrict__ sinT,
                                                     int nheads, int tstride) {
  int gw = (int)((blockIdx.x * blockDim.x + threadIdx.x) >> 6);
  int lane = threadIdx.x & 63;
  int t = gw / nheads, h = gw % nheads;
  unsigned short* row = q + (size_t)t * tstride + h * HDm;
  float x1 = b2f(row[lane]);
  float x2 = b2f(row[lane + 64]);
  float s = x1 * x1 + x2 * x2;
#pragma unroll
  for (int off = 32; off; off >>= 1) s += __shfl_xor(s, off);
  float r = rsqrtf(s * (1.f / HDm) + 1e-6f);
  float y1 = x1 * r * nrm[lane];
  float y2 = x2 * r * nrm[lane + 64];
  float c = cosT[t * 64 + lane];
  float sn = sinT[t * 64 + lane];
  row[lane]      = f2b(y1 * c - y2 * sn);
  row[lane + 64] = f2b(y2 * c + y1 * sn);
}

// Weight convert+transpose: W fp32 [K][N] -> Wt bf16 [N][K]
__global__ __launch_bounds__(256) void cvtT_k(const float* __restrict__ W,
                                              unsigned short* __restrict__ Wt,
                                              int K, int N) {
  __shared__ __align__(16) unsigned short tile[64][68];
  const int n0 = blockIdx.x * 64, k0 = blockIdx.y * 64;
  const int tid = threadIdx.x;
#pragma unroll
  for (int i = 0; i < 4; ++i) {
    int e = tid + i * 256;
    int r = e >> 4, c4 = (e & 15) * 4;
    f32x4 v = *(const f32x4*)(W + (size_t)(k0 + r) * N + n0 + c4);
    tile[r][c4 + 0] = f2b(v.x);
    tile[r][c4 + 1] = f2b(v.y);
    tile[r][c4 + 2] = f2b(v.z);
    tile[r][c4 + 3] = f2b(v.w);
  }
  __syncthreads();
#pragma unroll
  for (int i = 0; i < 2; ++i) {
    int e = tid + i * 256;
    int rr = e >> 3, cc = (e & 7) * 8;
    u16x8 o;
#pragma unroll
    for (int j = 0; j < 8; ++j) o[j] = tile[cc + j][rr];
    *(u16x8*)(Wt + (size_t)(n0 + rr) * K + k0 + cc) = o;
  }
}

// ---------------------------------------------------------------------------
// GEMM: C[M,N] = A[M,K] @ B^T. A bf16 [M][K]; B [N][K] (bf16, or fp32 if BF32).
// m97 structure: global_load_lds w=16, linear LDS [128][32], 2-barrier K-loop.
// EPI=0: store (bf16, or fp32 if OUTF32). EPI=1: C f32 +=. EPI=2: bf16 silu-mult.
template <int EPI, bool BF32, bool OUTF32>
__global__ __launch_bounds__(256) void gemm_k(const unsigned short* __restrict__ A,
                                              const void* __restrict__ B,
                                              void* __restrict__ C,
                                              int N, int K) {
  __shared__ __align__(16) unsigned short As[128 * 32];
  __shared__ __align__(16) unsigned short Bs[128 * 32];
  const int tid = threadIdx.x;
  const int nwg = gridDim.x * gridDim.y;
  const int nid = xcd_swz(blockIdx.x + gridDim.x * blockIdx.y, nwg);
  const int bm = nid % gridDim.x, bn = nid / gridDim.x;
  const int w = tid >> 6, lane = tid & 63;
  const int wm = (w >> 1) * 64, wn = (w & 1) * 64;
  const int lr = lane & 15, hi = lane >> 4, kq = hi * 8;
  const int rowA0 = bm * 128, colB0 = bn * 128;

  const int sr = lane >> 2;          // row within 16x32 chunk
  const int sc = (lane & 3) * 8;     // col (elems)
  const unsigned short* a0 = A + (size_t)(rowA0 + (w * 2 + 0) * 16 + sr) * K + sc;
  const unsigned short* a1 = A + (size_t)(rowA0 + (w * 2 + 1) * 16 + sr) * K + sc;
  unsigned short* la0 = &As[(w * 2 + 0) * 512];
  unsigned short* la1 = &As[(w * 2 + 1) * 512];
  const unsigned short* b0 = nullptr; const unsigned short* b1 = nullptr;
  unsigned short* lb0 = &Bs[(w * 2 + 0) * 512];
  unsigned short* lb1 = &Bs[(w * 2 + 1) * 512];
  if (!BF32) {
    b0 = (const unsigned short*)B + (size_t)(colB0 + (w * 2 + 0) * 16 + sr) * K + sc;
    b1 = (const unsigned short*)B + (size_t)(colB0 + (w * 2 + 1) * 16 + sr) * K + sc;
  }

  f32x4 acc[4][4] = {};

  for (int k0 = 0; k0 < K; k0 += 32) {
    __syncthreads();
    gload16(a0 + k0, la0);
    gload16(a1 + k0, la1);
    if (!BF32) {
      gload16(b0 + k0, lb0);
      gload16(b1 + k0, lb1);
    } else {
#pragma unroll
      for (int i = 0; i < 2; ++i) {
        int e = tid + i * 256;
        int rr = e >> 2, cc = (e & 3) * 8;
        const float* bp = (const float*)B + (size_t)(colB0 + rr) * K + k0 + cc;
        f32x4 v0 = *(const f32x4*)bp;
        f32x4 v1 = *(const f32x4*)(bp + 4);
        u16x8 o;
        o[0] = f2b(v0.x); o[1] = f2b(v0.y); o[2] = f2b(v0.z); o[3] = f2b(v0.w);
        o[4] = f2b(v1.x); o[5] = f2b(v1.y); o[6] = f2b(v1.z); o[7] = f2b(v1.w);
        *(u16x8*)&Bs[rr * 32 + cc] = o;
      }
    }
    __syncthreads();

    bf16x8 av[4], bv[4];
#pragma unroll
    for (int m = 0; m < 4; ++m)
      av[m] = __builtin_bit_cast(bf16x8, *(const u16x8*)&As[(wm + m * 16 + lr) * 32 + kq]);
#pragma unroll
    for (int n = 0; n < 4; ++n)
      bv[n] = __builtin_bit_cast(bf16x8, *(const u16x8*)&Bs[(wn + n * 16 + lr) * 32 + kq]);
#pragma unroll
    for (int m = 0; m < 4; ++m)
#pragma unroll
      for (int n = 0; n < 4; ++n)
        acc[m][n] = mfma16x16x32(av[m], bv[n], acc[m][n]);
  }

  const int r0 = rowA0 + wm + hi * 4;
  const int c0 = colB0 + wn + lr;
#pragma unroll
  for (int m = 0; m < 4; ++m)
#pragma unroll
    for (int n = 0; n < 4; ++n)
#pragma unroll
      for (int j = 0; j < 4; ++j) {
        int r = r0 + m * 16 + j;
        int c = c0 + n * 16;
        size_t idx = (size_t)r * N + c;
        if (EPI == 0) {
          if (OUTF32) ((float*)C)[idx] = acc[m][n][j];
          else        ((unsigned short*)C)[idx] = f2b(acc[m][n][j]);
        } else if (EPI == 1) {
          ((float*)C)[idx] += acc[m][n][j];
        } else {
          unsigned short* Cb = (unsigned short*)C;
          float gg = b2f(Cb[idx]);
          gg = gg / (1.f + __expf(-gg));   // silu of previously-stored h@W1
          Cb[idx] = f2b(gg * acc[m][n][j]);
        }
      }
}

// ---------------------------------------------------------------------------
// MFMA flash attention, GQA G=2, reading the fused qkv buffer [T][4096].
__global__ __launch_bounds__(256) void attn_k(const unsigned short* __restrict__ qkv,
                                              unsigned short* __restrict__ og) {
  __shared__ __align__(16) unsigned short Ks[64 * 128];
  __shared__ __align__(16) unsigned short Vt[128 * 72];
  __shared__ __align__(16) unsigned short Pl[4 * 16 * 72];
  const int h = blockIdx.y, bx = blockIdx.x, t0 = bx * 64;
  const int w = threadIdx.x >> 6, lane = threadIdx.x & 63;
  const int lr = lane & 15, hi = lane >> 4;
  const int kvh = h >> 1;
  const unsigned short* qg = qkv;
  const unsigned short* kg = qkv + 2048;
  const unsigned short* vg = qkv + 3072;

  bf16x8 qa[4];
  {
    const unsigned short* qrow = qg + (size_t)(t0 + w * 16 + lr) * QKVN + h * HDm;
#pragma unroll
    for (int ks = 0; ks < 4; ++ks)
      qa[ks] = __builtin_bit_cast(bf16x8, *(const u16x8*)(qrow + ks * 32 + hi * 8));
  }

  f32x4 oa[8] = {};
  float mj[4], lj[4];
#pragma unroll
  for (int j = 0; j < 4; ++j) { mj[j] = -3.0e38f; lj[j] = 0.f; }

  const int ntiles = bx + 1;
  for (int tile = 0; tile < ntiles; ++tile) {
    const int s0 = tile * 64;
    __syncthreads();
#pragma unroll
    for (int i = 0; i < 4; ++i) {
      int e = threadIdx.x + i * 256;
      int r = e >> 4, c = (e & 15) * 8;
      size_t base = (size_t)(s0 + r) * QKVN + kvh * HDm + c;
      u16x8 kk = *(const u16x8*)(kg + base);
      int kbyte = (r * 256 + c * 2) ^ ((r & 7) << 4);
      *(u16x8*)((char*)Ks + kbyte) = kk;
      u16x8 vv = *(const u16x8*)(vg + base);
#pragma unroll
      for (int j = 0; j < 8; ++j) {
        int d = c + j;
        Vt[d * 72 + (r ^ (((d >> 3) & 7) << 3))] = vv[j];
      }
    }
    __syncthreads();

    f32x4 s[4] = {};
#pragma unroll
    for (int ks = 0; ks < 4; ++ks)
#pragma unroll
      for (int nt = 0; nt < 4; ++nt) {
        int krow = nt * 16 + lr;
        int kbyte = (krow * 256 + (ks * 32 + hi * 8) * 2) ^ ((krow & 7) << 4);
        bf16x8 kf = __builtin_bit_cast(bf16x8, *(const u16x8*)((char*)Ks + kbyte));
        s[nt] = mfma16x16x32(qa[ks], kf, s[nt]);
      }

    float p[4][4];
    const bool maskt = (tile == ntiles - 1);
#pragma unroll
    for (int nt = 0; nt < 4; ++nt)
#pragma unroll
      for (int j = 0; j < 4; ++j) {
        float val = s[nt][j] * 0.08838834764831845f;
        if (maskt && (s0 + nt * 16 + lr) > (t0 + w * 16 + hi * 4 + j)) val = -1e30f;
        p[nt][j] = val;
      }

#pragma unroll
    for (int j = 0; j < 4; ++j) {
      float mx = fmaxf(fmaxf(p[0][j], p[1][j]), fmaxf(p[2][j], p[3][j]));
#pragma unroll
      for (int msk = 1; msk < 16; msk <<= 1) mx = fmaxf(mx, __shfl_xor(mx, msk));
      float mnew = fmaxf(mj[j], mx);
      float alpha = __expf(mj[j] - mnew);
      mj[j] = mnew;
      float sum = 0.f;
#pragma unroll
      for (int nt = 0; nt < 4; ++nt) {
        float e = __expf(p[nt][j] - mnew);
        p[nt][j] = e;
        sum += e;
      }
#pragma unroll
      for (int msk = 1; msk < 16; msk <<= 1) sum += __shfl_xor(sum, msk);
      lj[j] = lj[j] * alpha + sum;
#pragma unroll
      for (int nt2 = 0; nt2 < 8; ++nt2) oa[nt2][j] *= alpha;
    }

#pragma unroll
    for (int nt = 0; nt < 4; ++nt)
#pragma unroll
      for (int j = 0; j < 4; ++j)
        Pl[(w * 16 + hi * 4 + j) * 72 + nt * 16 + lr] = f2b(p[nt][j]);
    __builtin_amdgcn_sched_barrier(0);

    bf16x8 pa[2];
#pragma unroll
    for (int ks2 = 0; ks2 < 2; ++ks2)
      pa[ks2] = __builtin_bit_cast(bf16x8,
                 *(const u16x8*)&Pl[(w * 16 + lr) * 72 + ks2 * 32 + hi * 8]);
#pragma unroll
    for (int nt2 = 0; nt2 < 8; ++nt2)
#pragma unroll
      for (int ks2 = 0; ks2 < 2; ++ks2) {
        int d = nt2 * 16 + lr;
        int kv = ks2 * 32 + hi * 8;
        bf16x8 vf = __builtin_bit_cast(bf16x8,
                     *(const u16x8*)&Vt[d * 72 + (kv ^ (((d >> 3) & 7) << 3))]);
        oa[nt2] = mfma16x16x32(pa[ks2], vf, oa[nt2]);
      }
  }

#pragma unroll
  for (int nt2 = 0; nt2 < 8; ++nt2)
#pragma unroll
    for (int j = 0; j < 4; ++j) {
      int row = t0 + w * 16 + hi * 4 + j;
      int d = nt2 * 16 + lr;
      og[((size_t)row * Hm + h) * HDm + d] = f2b(oa[nt2][j] / lj[j]);
    }
}

// ---------------------------------------------------------------------------
extern "C" void kernel_launch(void* const* d_in, const int* in_sizes, int n_in,
                              void* d_out, int out_size, void* d_ws, size_t ws_size,
                              hipStream_t stream) {
  (void)in_sizes; (void)n_in; (void)out_size;
  const int*   ids = (const int*)d_in[0];
  const float* emb = (const float*)d_in[1];
  const float* Wq  = (const float*)d_in[2];
  const float* Wk  = (const float*)d_in[3];
  const float* Wv  = (const float*)d_in[4];
  const float* Wo  = (const float*)d_in[5];
  const float* qn  = (const float*)d_in[6];
  const float* kn  = (const float*)d_in[7];
  const float* W1  = (const float*)d_in[8];
  const float* W2  = (const float*)d_in[9];
  const float* W3  = (const float*)d_in[10];
  const float* ln1 = (const float*)d_in[11];
  const float* ln2 = (const float*)d_in[12];
  const float* lnf = (const float*)d_in[13];

  char* p = (char*)d_ws;
  float* xf           = (float*)p;          p += (size_t)Tm * Dm * 4;       // 16.78MB
  unsigned short* hb  = (unsigned short*)p; p += (size_t)Tm * Dm * 2;       //  8.39MB
  float* cosT         = (float*)p;          p += (size_t)Tm * 64 * 4;
  float* sinT         = (float*)p;          p += (size_t)Tm * 64 * 4;
  char* dyn           = p;                                                  // 26.2MB in
  unsigned short* qkv = (unsigned short*)p; p += (size_t)Tm * QKVN * 2;     // 16.78MB
  unsigned short* ob  = (unsigned short*)p; p += (size_t)Tm * Hm * HDm * 2; //  8.39MB
  unsigned short* wt  = (unsigned short*)p; p += (size_t)Dm * FFm * 2;      // 25.2MB
  unsigned short* g1  = qkv;  // FFN alias: qkv+ob span == T*FF*2 exactly
  unsigned short* embBf = (unsigned short*)dyn;  // 131MB overlay, logits phase only
  const size_t embBfEnd = (size_t)(dyn - (char*)d_ws) + (size_t)Vm * Dm * 2;
  const bool useEmbBf = ws_size >= embBfEnd;

  rope_tables_k<<<Tm, 64, 0, stream>>>(cosT, sinT);
  embed_k<<<Tm, 256, 0, stream>>>(ids, emb, xf);

  for (int l = 0; l < 2; ++l) {
    const float* Wq_l = Wq + (size_t)l * Dm * (Hm * HDm);
    const float* Wk_l = Wk + (size_t)l * Dm * (KVm * HDm);
    const float* Wv_l = Wv + (size_t)l * Dm * (KVm * HDm);
    const float* Wo_l = Wo + (size_t)l * (Hm * HDm) * Dm;
    const float* W1_l = W1 + (size_t)l * Dm * FFm;
    const float* W2_l = W2 + (size_t)l * Dm * FFm;
    const float* W3_l = W3 + (size_t)l * FFm * Dm;

    rmsnorm_k<<<Tm, 256, 0, stream>>>(xf, ln1 + (size_t)l * Dm, hb);

    // fused QKV: wt rows [0,2048)=Wq^T, [2048,3072)=Wk^T, [3072,4096)=Wv^T
    cvtT_k<<<dim3((Hm * HDm) / 64, Dm / 64), 256, 0, stream>>>(Wq_l, wt, Dm, Hm * HDm);
    cvtT_k<<<dim3((KVm * HDm) / 64, Dm / 64), 256, 0, stream>>>(
        Wk_l, wt + (size_t)2048 * Dm, Dm, KVm * HDm);
    cvtT_k<<<dim3((KVm * HDm) / 64, Dm / 64), 256, 0, stream>>>(
        Wv_l, wt + (size_t)3072 * Dm, Dm, KVm * HDm);
    gemm_k<0, false, false><<<dim3(Tm / 128, QKVN / 128), 256, 0, stream>>>(
        hb, wt, qkv, QKVN, Dm);

    qknorm_rope_k<<<(Tm * Hm) / 4, 256, 0, stream>>>(
        qkv, qn + (size_t)l * HDm, cosT, sinT, Hm, QKVN);
    qknorm_rope_k<<<(Tm * KVm) / 4, 256, 0, stream>>>(
        qkv + 2048, kn + (size_t)l * HDm, cosT, sinT, KVm, QKVN);

    attn_k<<<dim3(Tm / 64, Hm), 256, 0, stream>>>(qkv, ob);

    cvtT_k<<<dim3(Dm / 64, (Hm * HDm) / 64), 256, 0, stream>>>(Wo_l, wt, Hm * HDm, Dm);
    gemm_k<1, false, false><<<dim3(Tm / 128, Dm / 128), 256, 0, stream>>>(
        ob, wt, xf, Dm, Hm * HDm);

    rmsnorm_k<<<Tm, 256, 0, stream>>>(xf, ln2 + (size_t)l * Dm, hb);

    cvtT_k<<<dim3(FFm / 64, Dm / 64), 256, 0, stream>>>(W1_l, wt, Dm, FFm);
    gemm_k<0, false, false><<<dim3(Tm / 128, FFm / 128), 256, 0, stream>>>(
        hb, wt, g1, FFm, Dm);
    cvtT_k<<<dim3(FFm / 64, Dm / 64), 256, 0, stream>>>(W2_l, wt, Dm, FFm);
    gemm_k<2, false, false><<<dim3(Tm / 128, FFm / 128), 256, 0, stream>>>(
        hb, wt, g1, FFm, Dm);
    cvtT_k<<<dim3(Dm / 64, FFm / 64), 256, 0, stream>>>(W3_l, wt, FFm, Dm);
    gemm_k<1, false, false><<<dim3(Tm / 128, Dm / 128), 256, 0, stream>>>(
        g1, wt, xf, Dm, FFm);
  }

  rmsnorm_k<<<Tm, 256, 0, stream>>>(xf, lnf, hb);

  if (useEmbBf) {
    // one-time emb fp32->bf16 (qkv/ob/wt all dead now), then fast bf16 GEMM
    cvt_emb_k<<<((size_t)Vm * Dm) / (256 * 8), 256, 0, stream>>>(emb, embBf);
    gemm_k<0, false, true><<<dim3(Tm / 128, Vm / 128), 256, 0, stream>>>(
        hb, embBf, d_out, Vm, Dm);
  } else {
    gemm_k<0, true, true><<<dim3(Tm / 128, Vm / 128), 256, 0, stream>>>(
        hb, emb, d_out, Vm, Dm);
  }
}